// Round 5
// baseline (171.174 us; speedup 1.0000x reference)
//
#include <hip/hip_runtime.h>
#include <math.h>

#define INV2PI 0.15915494309189535f

typedef _Float16 f16;
typedef _Float16 f16x8 __attribute__((ext_vector_type(8)));
typedef _Float16 f16x4 __attribute__((ext_vector_type(4)));
typedef float f32x16 __attribute__((ext_vector_type(16)));

#define Z16 {0.f,0.f,0.f,0.f,0.f,0.f,0.f,0.f,0.f,0.f,0.f,0.f,0.f,0.f,0.f,0.f}

// workspace layout in FLOAT units
#define WS_MATS 0        // [2][8][2][16384] f16 = 524288 halves = 262144 floats
#define WS_TABS 262144   // [2][8][2][128] f32
#define WS_RY1  266240   // [2][14][2] f32
#define WS_XR   266304   // 64*14
#define WS_XR2  267200   // 64*14

// ---- precompute: gate Kron matrices (fp16), alpha tables, layer-1 ry ----
__global__ void k_pre(const float* __restrict__ w1, float* __restrict__ ws)
{
    int blk = blockIdx.x, t = threadIdx.x;
    if (blk < 32) {
        // blk = n*16 + (k-2)*2 + side ; side 0 = A (a-bits, wires 6-i), 1 = B (wires 13-i)
        int n = blk >> 4, rem = blk & 15, k = (rem >> 1) + 2, side = rem & 1;
        __shared__ float R[7][2][2];
        if (t < 7) {
            int wire = side ? (13 - t) : (6 - t);
            float th = w1[n*378 + (k-1)*42 + wire*3 + 1];
            float s, c; sincosf(0.5f*th, &s, &c);
            R[t][0][0] = c;  R[t][0][1] = -s;
            R[t][1][0] = s;  R[t][1][1] = c;
        }
        __syncthreads();
        f16* M = (f16*)ws + blk * 16384;
        for (int e = t; e < 16384; e += 256) {
            int o = e >> 7, ii = e & 127;
            float v = 1.f;
            #pragma unroll
            for (int bi = 0; bi < 7; ++bi) v *= R[bi][(o>>bi)&1][(ii>>bi)&1];
            M[e] = (f16)v;
        }
    } else if (blk == 32) {
        for (int e = t; e < 4096; e += 256) {
            int n = e >> 11, r = e & 2047, k = (r >> 8) + 1;
            int r2 = r & 255, side = r2 >> 7, v = r2 & 127;
            float acc = 0.f;
            #pragma unroll
            for (int bi = 0; bi < 7; ++bi) {
                if ((v >> bi) & 1) {
                    int wire = side ? (13 - bi) : (6 - bi);
                    acc += (w1[n*378 + (k-1)*42 + wire*3 + 2]
                          + w1[n*378 + k*42     + wire*3 + 0]) * INV2PI;
                }
            }
            ws[WS_TABS + ((n*8 + (k-1))*2 + side)*128 + v] = acc;
        }
    } else {
        if (t < 28) {
            int n = t / 14, q = t % 14;
            float th = w1[n*378 + q*3 + 1];
            float s, c; sincosf(0.5f*th, &s, &c);
            ws[WS_RY1 + (n*14 + q)*2 + 0] = c;
            ws[WS_RY1 + (n*14 + q)*2 + 1] = s;
        }
    }
}

// ---- linear_down ----
__global__ void k_down(const float* __restrict__ x, const float* __restrict__ wd,
                       const float* __restrict__ bd, float* __restrict__ xr)
{
    int row  = blockIdx.x;
    int wave = threadIdx.x >> 6;
    int lane = threadIdx.x & 63;
    const float* xrow = x + row * 784;
    for (int f = wave; f < 14; f += 4) {
        const float* wrow = wd + f * 784;
        float s = 0.f;
        for (int j = lane; j < 784; j += 64) s = fmaf(xrow[j], wrow[j], s);
        #pragma unroll
        for (int off = 32; off; off >>= 1) s += __shfl_xor(s, off);
        if (lane == 0) xr[row * 14 + f] = s + bd[f];
    }
}

// ---- circuit: per-row two-sided fp16 MFMA GEMM, diag in fp32 epilogues ----
// state d = (a<<7)|b ; a-bit i = wire 6-i ; b-bit i = wire 13-i
// layer k (2..9): P = k&1. P0: state rows=a; s1: A=state,B=MB -> I[b][a]; s2: A=MA,B=I -> S[b][a]
//                  P1: state rows=b; s1: A=state,B=MA -> I[a][b]; s2: A=MB,B=I -> S[a][b]
template<int WHICH>
__global__ __launch_bounds__(512)
void k_circuit(const f16* __restrict__ matsg, const float* __restrict__ tabsg,
               const float* __restrict__ ry1g, const float* __restrict__ xrin,
               float* __restrict__ xrout, const float* __restrict__ bnw,
               const float* __restrict__ bnb, const float* __restrict__ wu,
               const float* __restrict__ bu)
{
    __shared__ __align__(16) ushort SRe[16384];
    __shared__ __align__(16) ushort SIm[16384];
    __shared__ __align__(16) ushort IRe[16384];
    __shared__ __align__(16) ushort IIm[16384];
    __shared__ float TAB[8][2][128];
    __shared__ float PA[128], PB[128];
    __shared__ float XR[896];
    __shared__ float XROW[14];
    __shared__ float RED[8][15];

    const int row = blockIdx.x, T = threadIdx.x;

    for (int i = T; i < 896; i += 512) XR[i] = xrin[i];
    __syncthreads();
    if (T < 14) {   // BatchNorm (training-mode batch stats), output in revolutions
        float mu = 0.f;
        for (int r = 0; r < 64; ++r) mu += XR[r*14 + T];
        mu *= (1.f/64.f);
        float var = 0.f;
        for (int r = 0; r < 64; ++r) { float d = XR[r*14 + T] - mu; var += d*d; }
        var *= (1.f/64.f);
        float xb = (XR[row*14 + T] - mu) * rsqrtf(var + 1e-5f) * bnw[T] + bnb[T];
        XROW[T] = xb * INV2PI;
    }
    __syncthreads();
    for (int e = T; e < 2048; e += 512) {   // alpha tables, x folded at k=3,6
        int k0 = e >> 8, r2 = e & 255, side = r2 >> 7, v = r2 & 127;
        float val = tabsg[(k0*2 + side)*128 + v];
        if (k0 == 2 || k0 == 5) {
            #pragma unroll
            for (int bi = 0; bi < 7; ++bi)
                if ((v >> bi) & 1) val += XROW[side ? (13-bi) : (6-bi)];
        }
        TAB[k0][side][v] = val;
    }
    if (T < 256) {   // layer-1 product-state factors
        int side = T >> 7, v = T & 127;
        float p = 1.f;
        #pragma unroll
        for (int bi = 0; bi < 7; ++bi) {
            int wire = side ? (13-bi) : (6-bi);
            p *= ((v >> bi) & 1) ? ry1g[wire*2 + 1] : ry1g[wire*2];
        }
        if (side) PB[v] = p; else PA[v] = p;
    }
    __syncthreads();
    {   // init: S row-major [a][b] = pa*pb * e^{i*2pi*(tabA1+tabB1+0.5*czpar(d,1))}
        int a = T >> 2, b0 = (T & 3) << 5;
        float pav = PA[a], tA = TAB[0][0][a];
        #pragma unroll
        for (int j = 0; j < 32; j += 8) {
            f16 hr[8], hm[8];
            #pragma unroll
            for (int u = 0; u < 8; ++u) {
                int b = b0 + j + u;
                int d = (a << 7) | b;
                int rot = ((d >> 1) | (d << 13)) & 16383;
                float ang = tA + TAB[0][1][b] + 0.5f * (float)__popc(d & rot);
                float fr = __builtin_amdgcn_fractf(ang);
                float sn = __builtin_amdgcn_sinf(fr);
                float cs = __builtin_amdgcn_cosf(fr);
                float mg = pav * PB[b];
                hr[u] = (f16)(mg * cs);
                hm[u] = (f16)(mg * sn);
            }
            int hoff = ((a << 7) + b0 + j) ^ ((a & 15) << 3);
            f16x8 vr = {hr[0],hr[1],hr[2],hr[3],hr[4],hr[5],hr[6],hr[7]};
            f16x8 vi = {hm[0],hm[1],hm[2],hm[3],hm[4],hm[5],hm[6],hm[7]};
            *(f16x8*)((f16*)SRe + hoff) = vr;
            *(f16x8*)((f16*)SIm + hoff) = vi;
        }
    }
    __syncthreads();

    const int w  = T >> 6, l = T & 63, lm = l & 31, hb = l >> 5;
    const int tm = w >> 1, tn0 = (w & 1) * 2;
    const int mrow = tm*32 + lm;
    const int n0 = tn0*32 + lm, n1 = n0 + 32;

    float tot = 0.f;
    float bs[14];
    #pragma unroll
    for (int i = 0; i < 14; ++i) bs[i] = 0.f;

    #pragma unroll 1
    for (int k = 2; k <= 9; ++k) {
        const int P = k & 1;
        const f16* M1 = matsg + ((k-2)*2 + (P ? 0 : 1)) * 16384;
        const f16* M2 = matsg + ((k-2)*2 + (P ? 1 : 0)) * 16384;
        // ---- stage 1: A = state (LDS), B = M1 (global) -> I [n][m] ----
        {
            f32x16 a00 = Z16, a01 = Z16, a10 = Z16, a11 = Z16;
            #pragma unroll
            for (int kk = 0; kk < 8; ++kk) {
                int c0 = kk*16 + hb*8;
                int sa = ((mrow << 7) + c0) ^ ((mrow & 15) << 3);
                f16x8 Ar = *(const f16x8*)((const f16*)SRe + sa);
                f16x8 Ai = *(const f16x8*)((const f16*)SIm + sa);
                f16x8 B0 = *(const f16x8*)(M1 + n0*128 + c0);
                f16x8 B1 = *(const f16x8*)(M1 + n1*128 + c0);
                a00 = __builtin_amdgcn_mfma_f32_32x32x16_f16(Ar, B0, a00, 0,0,0);
                a01 = __builtin_amdgcn_mfma_f32_32x32x16_f16(Ai, B0, a01, 0,0,0);
                a10 = __builtin_amdgcn_mfma_f32_32x32x16_f16(Ar, B1, a10, 0,0,0);
                a11 = __builtin_amdgcn_mfma_f32_32x32x16_f16(Ai, B1, a11, 0,0,0);
            }
            #pragma unroll
            for (int tn = 0; tn < 2; ++tn) {
                int n = tn ? n1 : n0;
                #pragma unroll
                for (int g = 0; g < 4; ++g) {
                    int mb = tm*32 + g*8 + hb*4;
                    int hoff = ((n << 7) + mb) ^ ((n & 15) << 3);
                    f16 r0 = (f16)(tn ? a10[g*4+0] : a00[g*4+0]);
                    f16 r1 = (f16)(tn ? a10[g*4+1] : a00[g*4+1]);
                    f16 r2 = (f16)(tn ? a10[g*4+2] : a00[g*4+2]);
                    f16 r3 = (f16)(tn ? a10[g*4+3] : a00[g*4+3]);
                    f16 i0 = (f16)(tn ? a11[g*4+0] : a01[g*4+0]);
                    f16 i1 = (f16)(tn ? a11[g*4+1] : a01[g*4+1]);
                    f16 i2 = (f16)(tn ? a11[g*4+2] : a01[g*4+2]);
                    f16 i3 = (f16)(tn ? a11[g*4+3] : a01[g*4+3]);
                    f16x4 vr = {r0, r1, r2, r3};
                    f16x4 vi = {i0, i1, i2, i3};
                    *(f16x4*)((f16*)IRe + hoff) = vr;
                    *(f16x4*)((f16*)IIm + hoff) = vi;
                }
            }
        }
        __syncthreads();
        // ---- stage 2: A = M2 (global), B = I (LDS) -> S [n][m] + diag ----
        {
            f32x16 a00 = Z16, a01 = Z16, a10 = Z16, a11 = Z16;
            #pragma unroll
            for (int kk = 0; kk < 8; ++kk) {
                int c0 = kk*16 + hb*8;
                f16x8 A = *(const f16x8*)(M2 + mrow*128 + c0);
                int s0 = ((n0 << 7) + c0) ^ ((n0 & 15) << 3);
                int s1 = ((n1 << 7) + c0) ^ ((n1 & 15) << 3);
                f16x8 B0r = *(const f16x8*)((const f16*)IRe + s0);
                f16x8 B0i = *(const f16x8*)((const f16*)IIm + s0);
                f16x8 B1r = *(const f16x8*)((const f16*)IRe + s1);
                f16x8 B1i = *(const f16x8*)((const f16*)IIm + s1);
                a00 = __builtin_amdgcn_mfma_f32_32x32x16_f16(A, B0r, a00, 0,0,0);
                a01 = __builtin_amdgcn_mfma_f32_32x32x16_f16(A, B0i, a01, 0,0,0);
                a10 = __builtin_amdgcn_mfma_f32_32x32x16_f16(A, B1r, a10, 0,0,0);
                a11 = __builtin_amdgcn_mfma_f32_32x32x16_f16(A, B1i, a11, 0,0,0);
            }
            if (k < 9) {
                const float* tM = TAB[k-1][P ? 1 : 0];
                const float* tN = TAB[k-1][P ? 0 : 1];
                const int czr = ((k-1) % 3) + 1;
                #pragma unroll
                for (int tn = 0; tn < 2; ++tn) {
                    int n = tn ? n1 : n0;
                    float tNv = tN[n];
                    f16 pr[16], pi[16];
                    #pragma unroll
                    for (int r = 0; r < 16; ++r) {
                        int mloc = (r & 3) + 8*(r >> 2) + 4*hb;
                        int mg = tm*32 + mloc;
                        int d  = P ? ((n << 7) | mg) : ((mg << 7) | n);
                        int rot = ((d >> czr) | (d << (14 - czr))) & 16383;
                        float ang = tM[mg] + tNv + 0.5f * (float)__popc(d & rot);
                        float fr = __builtin_amdgcn_fractf(ang);
                        float sn = __builtin_amdgcn_sinf(fr);
                        float cs = __builtin_amdgcn_cosf(fr);
                        float re = tn ? a10[r] : a00[r];
                        float im = tn ? a11[r] : a01[r];
                        pr[r] = (f16)(re*cs - im*sn);
                        pi[r] = (f16)(re*sn + im*cs);
                    }
                    #pragma unroll
                    for (int g = 0; g < 4; ++g) {
                        int mb = tm*32 + g*8 + hb*4;
                        int hoff = ((n << 7) + mb) ^ ((n & 15) << 3);
                        f16x4 vr = {pr[g*4], pr[g*4+1], pr[g*4+2], pr[g*4+3]};
                        f16x4 vi = {pi[g*4], pi[g*4+1], pi[g*4+2], pi[g*4+3]};
                        *(f16x4*)((f16*)SRe + hoff) = vr;
                        *(f16x4*)((f16*)SIm + hoff) = vi;
                    }
                }
            } else {   // k=9 (P1: m=b, n=a): measure from fp32 accumulators
                #pragma unroll
                for (int tn = 0; tn < 2; ++tn) {
                    int a = tn ? n1 : n0;
                    float tp = 0.f, s0 = 0.f, s1v = 0.f, s3 = 0.f, s4 = 0.f;
                    #pragma unroll
                    for (int r = 0; r < 16; ++r) {
                        float re = tn ? a10[r] : a00[r];
                        float im = tn ? a11[r] : a01[r];
                        float p = fmaf(re, re, im*im);
                        tp += p;
                        if (r & 1) s0  += p;
                        if (r & 2) s1v += p;
                        if (r & 4) s3  += p;
                        if (r & 8) s4  += p;
                    }
                    tot += tp;
                    bs[0] += s0; bs[1] += s1v; bs[3] += s3; bs[4] += s4;
                    if (hb)     bs[2] += tp;
                    if (tm & 1) bs[5] += tp;
                    if (tm & 2) bs[6] += tp;
                    #pragma unroll
                    for (int i = 0; i < 7; ++i)
                        if ((a >> i) & 1) bs[7+i] += tp;
                }
            }
        }
        __syncthreads();
    }

    #pragma unroll
    for (int off = 32; off; off >>= 1) {
        tot += __shfl_xor(tot, off);
        #pragma unroll
        for (int i = 0; i < 14; ++i) bs[i] += __shfl_xor(bs[i], off);
    }
    if (l == 0) {
        #pragma unroll
        for (int i = 0; i < 14; ++i) RED[w][i] = bs[i];
        RED[w][14] = tot;
    }
    __syncthreads();
    if (T < 14) {
        float tt = 0.f, ss = 0.f;
        #pragma unroll
        for (int ww = 0; ww < 8; ++ww) { tt += RED[ww][14]; ss += RED[ww][13 - T]; }
        float val = tt - 2.f * ss;
        XROW[T] = val;
        if (WHICH == 0) xrout[row*14 + T] = val;
    }
    __syncthreads();
    if (WHICH == 1) {   // fused linear_up
        for (int j = T; j < 784; j += 512) {
            float s = bu[j];
            #pragma unroll
            for (int f = 0; f < 14; ++f) s = fmaf(XROW[f], wu[j*14 + f], s);
            xrout[row*784 + j] = s;
        }
    }
}

extern "C" void kernel_launch(void* const* d_in, const int* in_sizes, int n_in,
                              void* d_out, int out_size, void* d_ws, size_t ws_size,
                              hipStream_t stream)
{
    const float* x  = (const float*)d_in[0];
    const float* wd = (const float*)d_in[1];
    const float* bd = (const float*)d_in[2];
    const float* bw = (const float*)d_in[3];
    const float* bb = (const float*)d_in[4];
    const float* w1 = (const float*)d_in[5];
    const float* wu = (const float*)d_in[6];
    const float* bu = (const float*)d_in[7];
    float* out = (float*)d_out;
    float* ws  = (float*)d_ws;

    hipLaunchKernelGGL(k_pre,  dim3(34), dim3(256), 0, stream, w1, ws);
    hipLaunchKernelGGL(k_down, dim3(64), dim3(256), 0, stream, x, wd, bd, ws + WS_XR);

    const f16* mats0 = (const f16*)ws;
    const f16* mats1 = (const f16*)ws + 262144;
    hipLaunchKernelGGL(k_circuit<0>, dim3(64), dim3(512), 0, stream,
                       mats0, ws + WS_TABS, ws + WS_RY1,
                       ws + WS_XR, ws + WS_XR2, bw, bb, wu, bu);
    hipLaunchKernelGGL(k_circuit<1>, dim3(64), dim3(512), 0, stream,
                       mats1, ws + WS_TABS + 2048, ws + WS_RY1 + 28,
                       ws + WS_XR2, out, bw, bb, wu, bu);
}

// Round 6
// 133.552 us; speedup vs baseline: 1.2817x; 1.2817x over previous
//
#include <hip/hip_runtime.h>
#include <math.h>

#define INV2PI 0.15915494309189535f

typedef _Float16 f16;
typedef _Float16 f16x8 __attribute__((ext_vector_type(8)));
typedef _Float16 f16x4 __attribute__((ext_vector_type(4)));
typedef float f32x16 __attribute__((ext_vector_type(16)));

#define Z16 {0.f,0.f,0.f,0.f,0.f,0.f,0.f,0.f,0.f,0.f,0.f,0.f,0.f,0.f,0.f,0.f}

// workspace layout in FLOAT units
#define WS_MATS 0        // [2][8][2][16384] f16 (fragment-major) = 262144 floats
#define WS_TABS 262144   // [2][8][2][128] f32 (revolutions)
#define WS_RY1  266240   // [2][14][2] f32
#define WS_XR   266304   // 64*14
#define WS_XR2  267200   // 64*14

// ---- precompute: gate Kron matrices (fp16, MFMA-fragment-major), alpha tables, ry1
__global__ void k_pre(const float* __restrict__ w1, float* __restrict__ ws)
{
    int blk = blockIdx.x, t = threadIdx.x;
    if (blk < 32) {
        // blk = n*16 + (k-2)*2 + side ; side 0 = A (a-bits, wires 6-i), 1 = B (wires 13-i)
        int n = blk >> 4, rem = blk & 15, k = (rem >> 1) + 2, side = rem & 1;
        __shared__ float R[7][2][2];
        if (t < 7) {
            int wire = side ? (13 - t) : (6 - t);
            float th = w1[n*378 + (k-1)*42 + wire*3 + 1];
            float s, c; sincosf(0.5f*th, &s, &c);
            R[t][0][0] = c;  R[t][0][1] = -s;
            R[t][1][0] = s;  R[t][1][1] = c;
        }
        __syncthreads();
        // fragment-major: flat = (tile<<12)|(kk<<9)|(l<<3)|j
        // row = tile*32 + (l&31); col = kk*16 + (l>>5)*8 + j; M[row][col]
        f16* M = (f16*)ws + blk * 16384;
        for (int e = t; e < 16384; e += 256) {
            int tile = e >> 12, kk = (e >> 9) & 7, l = (e >> 3) & 63, j = e & 7;
            int row = tile*32 + (l & 31);
            int col = kk*16 + (l >> 5)*8 + j;
            float v = 1.f;
            #pragma unroll
            for (int bi = 0; bi < 7; ++bi) v *= R[bi][(row>>bi)&1][(col>>bi)&1];
            M[e] = (f16)v;
        }
    } else if (blk == 32) {
        for (int e = t; e < 4096; e += 256) {
            int n = e >> 11, r = e & 2047, k = (r >> 8) + 1;
            int r2 = r & 255, side = r2 >> 7, v = r2 & 127;
            float acc = 0.f;
            #pragma unroll
            for (int bi = 0; bi < 7; ++bi) {
                if ((v >> bi) & 1) {
                    int wire = side ? (13 - bi) : (6 - bi);
                    acc += (w1[n*378 + (k-1)*42 + wire*3 + 2]
                          + w1[n*378 + k*42     + wire*3 + 0]) * INV2PI;
                }
            }
            ws[WS_TABS + ((n*8 + (k-1))*2 + side)*128 + v] = acc;
        }
    } else {
        if (t < 28) {
            int n = t / 14, q = t % 14;
            float th = w1[n*378 + q*3 + 1];
            float s, c; sincosf(0.5f*th, &s, &c);
            ws[WS_RY1 + (n*14 + q)*2 + 0] = c;
            ws[WS_RY1 + (n*14 + q)*2 + 1] = s;
        }
    }
}

// ---- linear_down ----
__global__ void k_down(const float* __restrict__ x, const float* __restrict__ wd,
                       const float* __restrict__ bd, float* __restrict__ xr)
{
    int row  = blockIdx.x;
    int wave = threadIdx.x >> 6;
    int lane = threadIdx.x & 63;
    const float* xrow = x + row * 784;
    for (int f = wave; f < 14; f += 4) {
        const float* wrow = wd + f * 784;
        float s = 0.f;
        for (int j = lane; j < 784; j += 64) s = fmaf(xrow[j], wrow[j], s);
        #pragma unroll
        for (int off = 32; off; off >>= 1) s += __shfl_xor(s, off);
        if (lane == 0) xr[row * 14 + f] = s + bd[f];
    }
}

// ---- circuit: 1024 thr / 16 waves, one 32x32 tile per wave, ETAB diag ----
template<int WHICH>
__global__ __launch_bounds__(1024)
void k_circuit(const f16* __restrict__ matsg, const float* __restrict__ tabsg,
               const float* __restrict__ ry1g, const float* __restrict__ xrin,
               float* __restrict__ xrout, const float* __restrict__ bnw,
               const float* __restrict__ bnb, const float* __restrict__ wu,
               const float* __restrict__ bu)
{
    __shared__ __align__(16) ushort SRe[16384];
    __shared__ __align__(16) ushort SIm[16384];
    __shared__ __align__(16) ushort IRe[16384];
    __shared__ __align__(16) ushort IIm[16384];
    __shared__ float2 ETAB[8][2][128];
    __shared__ float PA[128], PB[128];
    __shared__ float XR[896];
    __shared__ float XROW[14];
    __shared__ float RED[16][15];

    const int row = blockIdx.x, T = threadIdx.x;
    const int w = T >> 6, l = T & 63, lm = l & 31, hb = l >> 5;
    const int tm = w >> 2, tn = w & 3;
    const int mrow = tm*32 + lm, nn = tn*32 + lm;

    for (int i = T; i < 896; i += 1024) XR[i] = xrin[i];
    __syncthreads();
    if (T < 14) {   // BatchNorm (batch stats), output in revolutions
        float mu = 0.f;
        for (int r = 0; r < 64; ++r) mu += XR[r*14 + T];
        mu *= (1.f/64.f);
        float var = 0.f;
        for (int r = 0; r < 64; ++r) { float d = XR[r*14 + T] - mu; var += d*d; }
        var *= (1.f/64.f);
        float xb = (XR[row*14 + T] - mu) * rsqrtf(var + 1e-5f) * bnw[T] + bnb[T];
        XROW[T] = xb * INV2PI;
    }
    __syncthreads();
    for (int e = T; e < 2048; e += 1024) {  // ETAB: e^{2πi·(alpha [+x at k=3,6])}
        int k0 = e >> 8, r2 = e & 255, side = r2 >> 7, v = r2 & 127;
        float val = tabsg[(k0*2 + side)*128 + v];
        if (k0 == 2 || k0 == 5) {
            #pragma unroll
            for (int bi = 0; bi < 7; ++bi)
                if ((v >> bi) & 1) val += XROW[side ? (13-bi) : (6-bi)];
        }
        float fr = __builtin_amdgcn_fractf(val);
        ETAB[k0][side][v] = make_float2(__builtin_amdgcn_cosf(fr),
                                        __builtin_amdgcn_sinf(fr));
    }
    if (T < 256) {   // layer-1 product-state factors
        int side = T >> 7, v = T & 127;
        float p = 1.f;
        #pragma unroll
        for (int bi = 0; bi < 7; ++bi) {
            int wire = side ? (13-bi) : (6-bi);
            p *= ((v >> bi) & 1) ? ry1g[wire*2 + 1] : ry1g[wire*2];
        }
        if (side) PB[v] = p; else PA[v] = p;
    }
    __syncthreads();
    {   // init: S[a][b] = pa*pb * eA[a]*eB[b] * (-1)^{czpar(d,1)}
        int a = T >> 3, b0 = (T & 7) << 4;
        float2 eA = ETAB[0][0][a];
        float pav = PA[a];
        #pragma unroll
        for (int g = 0; g < 2; ++g) {
            f16 hr[8], hm[8];
            #pragma unroll
            for (int u = 0; u < 8; ++u) {
                int b = b0 + g*8 + u;
                int d = (a << 7) | b;
                int rot = ((d >> 1) | (d << 13)) & 16383;
                float2 eB = ETAB[0][1][b];
                float zr = eA.x*eB.x - eA.y*eB.y;
                float zi = eA.x*eB.y + eA.y*eB.x;
                if (__popc(d & rot) & 1) { zr = -zr; zi = -zi; }
                float mg = pav * PB[b];
                hr[u] = (f16)(mg * zr);
                hm[u] = (f16)(mg * zi);
            }
            int hoff = ((a << 7) + b0 + g*8) ^ ((a & 15) << 3);
            f16x8 vr = {hr[0],hr[1],hr[2],hr[3],hr[4],hr[5],hr[6],hr[7]};
            f16x8 vi = {hm[0],hm[1],hm[2],hm[3],hm[4],hm[5],hm[6],hm[7]};
            *(f16x8*)((f16*)SRe + hoff) = vr;
            *(f16x8*)((f16*)SIm + hoff) = vi;
        }
    }
    __syncthreads();

    float tot = 0.f;
    float bs[14];
    #pragma unroll
    for (int i = 0; i < 14; ++i) bs[i] = 0.f;

    #pragma unroll 1
    for (int k = 2; k <= 9; ++k) {
        const int P = k & 1;
        const f16* M1 = matsg + ((k-2)*2 + (P ? 0 : 1)) * 16384;
        const f16* M2 = matsg + ((k-2)*2 + (P ? 1 : 0)) * 16384;
        // prefetch all stage-1 B fragments (coalesced 1KB/wave each)
        f16x8 Bf[8];
        #pragma unroll
        for (int kk = 0; kk < 8; ++kk)
            Bf[kk] = *(const f16x8*)(M1 + (tn*8 + kk)*512 + l*8);
        // ---- stage 1: I[n][m] = sum_c S[m][c] * M1[n][c] ----
        f32x16 ar = Z16, ai = Z16;
        #pragma unroll
        for (int kk = 0; kk < 8; ++kk) {
            int c  = kk*16 + hb*8;
            int sa = ((mrow << 7) + c) ^ ((mrow & 15) << 3);
            f16x8 Ar = *(const f16x8*)((const f16*)SRe + sa);
            f16x8 Ai = *(const f16x8*)((const f16*)SIm + sa);
            ar = __builtin_amdgcn_mfma_f32_32x32x16_f16(Ar, Bf[kk], ar, 0,0,0);
            ai = __builtin_amdgcn_mfma_f32_32x32x16_f16(Ai, Bf[kk], ai, 0,0,0);
        }
        // prefetch stage-2 A fragments (latency hidden by store+barrier)
        f16x8 Af[8];
        #pragma unroll
        for (int kk = 0; kk < 8; ++kk)
            Af[kk] = *(const f16x8*)(M2 + (tm*8 + kk)*512 + l*8);
        #pragma unroll
        for (int g = 0; g < 4; ++g) {
            int mb = tm*32 + g*8 + hb*4;
            int hoff = ((nn << 7) + mb) ^ ((nn & 15) << 3);
            f16x4 vr = {(f16)ar[g*4],(f16)ar[g*4+1],(f16)ar[g*4+2],(f16)ar[g*4+3]};
            f16x4 vi = {(f16)ai[g*4],(f16)ai[g*4+1],(f16)ai[g*4+2],(f16)ai[g*4+3]};
            *(f16x4*)((f16*)IRe + hoff) = vr;
            *(f16x4*)((f16*)IIm + hoff) = vi;
        }
        __syncthreads();
        // ---- stage 2: S'[n][m'] = sum_c M2[m'][c] * I[n][c] (+ diag) ----
        f32x16 dr = Z16, di = Z16;
        #pragma unroll
        for (int kk = 0; kk < 8; ++kk) {
            int c  = kk*16 + hb*8;
            int s0 = ((nn << 7) + c) ^ ((nn & 15) << 3);
            f16x8 Br = *(const f16x8*)((const f16*)IRe + s0);
            f16x8 Bi = *(const f16x8*)((const f16*)IIm + s0);
            dr = __builtin_amdgcn_mfma_f32_32x32x16_f16(Af[kk], Br, dr, 0,0,0);
            di = __builtin_amdgcn_mfma_f32_32x32x16_f16(Af[kk], Bi, di, 0,0,0);
        }
        if (k < 9) {
            float2 eN = ETAB[k-1][P ? 0 : 1][nn];
            const int czr = ((k-1) % 3) + 1;
            f16 pr[16], pi[16];
            #pragma unroll
            for (int r = 0; r < 16; ++r) {
                int mloc = (r & 3) + 8*(r >> 2) + 4*hb;
                int mg = tm*32 + mloc;
                float2 eM = ETAB[k-1][P ? 1 : 0][mg];
                int d = P ? ((nn << 7) | mg) : ((mg << 7) | nn);
                int rot = ((d >> czr) | (d << (14 - czr))) & 16383;
                float zr = eM.x*eN.x - eM.y*eN.y;
                float zi = eM.x*eN.y + eM.y*eN.x;
                if (__popc(d & rot) & 1) { zr = -zr; zi = -zi; }
                float re = dr[r], im = di[r];
                pr[r] = (f16)(re*zr - im*zi);
                pi[r] = (f16)(re*zi + im*zr);
            }
            #pragma unroll
            for (int g = 0; g < 4; ++g) {
                int mb = tm*32 + g*8 + hb*4;
                int hoff = ((nn << 7) + mb) ^ ((nn & 15) << 3);
                f16x4 vr = {pr[g*4], pr[g*4+1], pr[g*4+2], pr[g*4+3]};
                f16x4 vi = {pi[g*4], pi[g*4+1], pi[g*4+2], pi[g*4+3]};
                *(f16x4*)((f16*)SRe + hoff) = vr;
                *(f16x4*)((f16*)SIm + hoff) = vi;
            }
        } else {   // k=9 (P1: m=b, n=a): measure from fp32 accumulators
            float tp = 0.f, s0 = 0.f, s1v = 0.f, s3 = 0.f, s4 = 0.f;
            #pragma unroll
            for (int r = 0; r < 16; ++r) {
                float re = dr[r], im = di[r];
                float p = fmaf(re, re, im*im);
                tp += p;
                if (r & 1) s0  += p;
                if (r & 2) s1v += p;
                if (r & 4) s3  += p;
                if (r & 8) s4  += p;
            }
            tot += tp;
            bs[0] += s0; bs[1] += s1v; bs[3] += s3; bs[4] += s4;
            if (hb)     bs[2] += tp;
            if (tm & 1) bs[5] += tp;
            if (tm & 2) bs[6] += tp;
            #pragma unroll
            for (int i = 0; i < 7; ++i)
                if ((nn >> i) & 1) bs[7+i] += tp;
        }
        __syncthreads();
    }

    #pragma unroll
    for (int off = 32; off; off >>= 1) {
        tot += __shfl_xor(tot, off);
        #pragma unroll
        for (int i = 0; i < 14; ++i) bs[i] += __shfl_xor(bs[i], off);
    }
    if (l == 0) {
        #pragma unroll
        for (int i = 0; i < 14; ++i) RED[w][i] = bs[i];
        RED[w][14] = tot;
    }
    __syncthreads();
    if (T < 14) {
        float tt = 0.f, ss = 0.f;
        #pragma unroll
        for (int ww = 0; ww < 16; ++ww) { tt += RED[ww][14]; ss += RED[ww][13 - T]; }
        float val = tt - 2.f * ss;
        XROW[T] = val;
        if (WHICH == 0) xrout[row*14 + T] = val;
    }
    __syncthreads();
    if (WHICH == 1) {   // fused linear_up
        for (int j = T; j < 784; j += 1024) {
            float s = bu[j];
            #pragma unroll
            for (int f = 0; f < 14; ++f) s = fmaf(XROW[f], wu[j*14 + f], s);
            xrout[row*784 + j] = s;
        }
    }
}

extern "C" void kernel_launch(void* const* d_in, const int* in_sizes, int n_in,
                              void* d_out, int out_size, void* d_ws, size_t ws_size,
                              hipStream_t stream)
{
    const float* x  = (const float*)d_in[0];
    const float* wd = (const float*)d_in[1];
    const float* bd = (const float*)d_in[2];
    const float* bw = (const float*)d_in[3];
    const float* bb = (const float*)d_in[4];
    const float* w1 = (const float*)d_in[5];
    const float* wu = (const float*)d_in[6];
    const float* bu = (const float*)d_in[7];
    float* out = (float*)d_out;
    float* ws  = (float*)d_ws;

    hipLaunchKernelGGL(k_pre,  dim3(34), dim3(256), 0, stream, w1, ws);
    hipLaunchKernelGGL(k_down, dim3(64), dim3(256), 0, stream, x, wd, bd, ws + WS_XR);

    const f16* mats0 = (const f16*)ws;
    const f16* mats1 = (const f16*)ws + 262144;
    hipLaunchKernelGGL(k_circuit<0>, dim3(64), dim3(1024), 0, stream,
                       mats0, ws + WS_TABS, ws + WS_RY1,
                       ws + WS_XR, ws + WS_XR2, bw, bb, wu, bu);
    hipLaunchKernelGGL(k_circuit<1>, dim3(64), dim3(1024), 0, stream,
                       mats1, ws + WS_TABS + 2048, ws + WS_RY1 + 28,
                       ws + WS_XR2, out, bw, bb, wu, bu);
}